// Round 1
// baseline (1113.532 us; speedup 1.0000x reference)
//
#include <hip/hip_runtime.h>
#include <hip/hip_bf16.h>
#include <cstdint>

#define V_ 25
#define T_ 128
#define VT_ 3200
#define NVTF_ 204800.0f

// ---------------- a1/a2: (N,16,V,T) = wg @ x ----------------
__global__ __launch_bounds__(128) void k_a(const float* __restrict__ x,
        const float* __restrict__ wg1, const float* __restrict__ wg2,
        float* __restrict__ a1, float* __restrict__ a2) {
    int b = blockIdx.x; int n = b / V_; int v = b % V_;
    int t = threadIdx.x;
    __shared__ float w1s[1024], w2s[1024];
    for (int i = threadIdx.x; i < 1024; i += 128) { w1s[i] = wg1[i]; w2s[i] = wg2[i]; }
    __syncthreads();
    float s1[16], s2[16];
    #pragma unroll
    for (int o = 0; o < 16; o++) { s1[o] = 0.f; s2[o] = 0.f; }
    const float* xp = x + (size_t)n * 204800 + v * T_ + t;
    for (int c = 0; c < 64; c++) {
        float xv = xp[(size_t)c * VT_];
        #pragma unroll
        for (int o = 0; o < 16; o++) {
            s1[o] = fmaf(w1s[o*64+c], xv, s1[o]);
            s2[o] = fmaf(w2s[o*64+c], xv, s2[o]);
        }
    }
    float* p1 = a1 + (size_t)n * 51200 + v * T_ + t;
    float* p2 = a2 + (size_t)n * 51200 + v * T_ + t;
    #pragma unroll
    for (int o = 0; o < 16; o++) { p1[(size_t)o*VT_] = s1[o]; p2[(size_t)o*VT_] = s2[o]; }
}

// ---------------- g = softmax(a1^T a2) per (n,t): (N,T,V,V) ----------------
__global__ __launch_bounds__(256) void k_g(const float* __restrict__ a1,
        const float* __restrict__ a2, float* __restrict__ g) {
    int n = blockIdx.x >> 3; int t0 = (blockIdx.x & 7) * 16;
    __shared__ float A1s[6400], A2s[6400]; // [o][v][tt]
    for (int i = threadIdx.x; i < 6400; i += 256) {
        int o = i / 400; int r = i % 400; int v = r >> 4; int tt = r & 15;
        size_t ga = (size_t)n * 51200 + (size_t)o * VT_ + v * T_ + t0 + tt;
        A1s[i] = a1[ga];
        A2s[i] = a2[ga];
    }
    __syncthreads();
    for (int r = threadIdx.x; r < 400; r += 256) {
        int v = r >> 4; int tt = r & 15;
        float a1r[16];
        #pragma unroll
        for (int o = 0; o < 16; o++) a1r[o] = A1s[o*400 + v*16 + tt];
        float gr[25];
        float mx = -1e30f;
        for (int u = 0; u < 25; u++) {
            float s = 0.f;
            #pragma unroll
            for (int o = 0; o < 16; o++) s = fmaf(a1r[o], A2s[o*400 + u*16 + tt], s);
            gr[u] = s; mx = fmaxf(mx, s);
        }
        float sum = 0.f;
        for (int u = 0; u < 25; u++) { gr[u] = __expf(gr[u] - mx); sum += gr[u]; }
        float inv = 1.f / sum;
        float* gp = g + ((size_t)(n * T_ + t0 + tt) * V_ + v) * V_;
        for (int u = 0; u < 25; u++) gp[u] = gr[u] * inv;
    }
}

// ---------------- x1[n,c,v,t] = sum_u g[n,t,v,u] * x[n,c,u,t] ----------------
__global__ __launch_bounds__(256) void k_mp(const float* __restrict__ xin,
        const float* __restrict__ g, float* __restrict__ x1, int C) {
    int n = blockIdx.x >> 3; int t0 = (blockIdx.x & 7) * 16;
    __shared__ float Gs[10400]; // [tt][v][u] padded u->26
    __shared__ float Xs[400];   // [u][tt]
    for (int i = threadIdx.x; i < 10000; i += 256) {
        int tt = i / 625; int r = i % 625; int v = r / 25; int u = r % 25;
        Gs[(tt*25 + v)*26 + u] = g[((size_t)(n*T_ + t0 + tt) * V_ + v) * V_ + u];
    }
    for (int c = 0; c < C; c++) {
        __syncthreads();
        for (int i = threadIdx.x; i < 400; i += 256) {
            int u = i >> 4; int tt = i & 15;
            Xs[u*16 + tt] = xin[((size_t)n * C + c) * VT_ + u * T_ + t0 + tt];
        }
        __syncthreads();
        for (int i = threadIdx.x; i < 400; i += 256) {
            int v = i >> 4; int tt = i & 15;
            float acc = 0.f;
            #pragma unroll
            for (int u = 0; u < 25; u++)
                acc = fmaf(Gs[(tt*25 + v)*26 + u], Xs[u*16 + tt], acc);
            x1[((size_t)n * C + c) * VT_ + v * T_ + t0 + tt] = acc;
        }
    }
}

// ---------------- y = [W1|W2] @ [x1;xin] per n, + per-block BN partial stats ----------------
__global__ __launch_bounds__(256) void k_gemm(const float* __restrict__ w1,
        const float* __restrict__ w2, const float* __restrict__ x1,
        const float* __restrict__ xin, float* __restrict__ y,
        float* __restrict__ psum, float* __restrict__ psq, int C, int O) {
    int n = blockIdx.z;
    int m0 = blockIdx.x * 128;
    int o0 = blockIdx.y * 64;
    int tx = threadIdx.x & 15, ty = threadIdx.x >> 4;
    __shared__ float As[16][68];
    __shared__ float Bs[16][128];
    float acc[4][8];
    #pragma unroll
    for (int i = 0; i < 4; i++)
        #pragma unroll
        for (int j = 0; j < 8; j++) acc[i][j] = 0.f;
    int K = 2 * C;
    for (int k0 = 0; k0 < K; k0 += 16) {
        const float* wsrc = (k0 < C) ? w1 : w2;
        const float* bsrc = (k0 < C) ? x1 : xin;
        int kk = (k0 < C) ? k0 : k0 - C;
        for (int i = threadIdx.x; i < 1024; i += 256) {
            int o = i >> 4, k = i & 15;
            As[k][o] = wsrc[(o0 + o) * C + kk + k];
        }
        for (int i = threadIdx.x; i < 2048; i += 256) {
            int k = i >> 7, m = i & 127;
            Bs[k][m] = bsrc[((size_t)n * C + kk + k) * VT_ + m0 + m];
        }
        __syncthreads();
        #pragma unroll
        for (int k = 0; k < 16; k++) {
            float a[4], bb[8];
            #pragma unroll
            for (int i = 0; i < 4; i++) a[i] = As[k][ty*4+i];
            #pragma unroll
            for (int j = 0; j < 8; j++) bb[j] = Bs[k][tx*8+j];
            #pragma unroll
            for (int i = 0; i < 4; i++)
                #pragma unroll
                for (int j = 0; j < 8; j++)
                    acc[i][j] = fmaf(a[i], bb[j], acc[i][j]);
        }
        __syncthreads();
    }
    size_t ybase = ((size_t)n * O + o0) * VT_ + m0;
    #pragma unroll
    for (int i = 0; i < 4; i++) {
        float* yp = y + ybase + (size_t)(ty*4+i) * VT_ + tx*8;
        float4 v0 = make_float4(acc[i][0], acc[i][1], acc[i][2], acc[i][3]);
        float4 v1 = make_float4(acc[i][4], acc[i][5], acc[i][6], acc[i][7]);
        *(float4*)yp = v0;
        *(float4*)(yp + 4) = v1;
        float s = 0.f, q = 0.f;
        #pragma unroll
        for (int j = 0; j < 8; j++) { s += acc[i][j]; q = fmaf(acc[i][j], acc[i][j], q); }
        #pragma unroll
        for (int msk = 1; msk < 16; msk <<= 1) { s += __shfl_xor(s, msk, 16); q += __shfl_xor(q, msk, 16); }
        if (tx == 0) {
            int o = o0 + ty*4 + i;
            int p = n * gridDim.x + blockIdx.x;  // 0..1599
            psum[(size_t)o * 1600 + p] = s;
            psq [(size_t)o * 1600 + p] = q;
        }
    }
}

// ---------------- finalize per-channel stats -> scale/shift ----------------
__global__ __launch_bounds__(256) void k_stats(const float* __restrict__ psum,
        const float* __restrict__ psq, const float* __restrict__ gamma,
        const float* __restrict__ beta, float* __restrict__ bnp) {
    int o = blockIdx.x;
    float s = 0.f, q = 0.f;
    for (int i = threadIdx.x; i < 1600; i += 256) { s += psum[(size_t)o*1600+i]; q += psq[(size_t)o*1600+i]; }
    __shared__ float rs[256], rq[256];
    rs[threadIdx.x] = s; rq[threadIdx.x] = q;
    __syncthreads();
    for (int st = 128; st > 0; st >>= 1) {
        if (threadIdx.x < st) { rs[threadIdx.x] += rs[threadIdx.x+st]; rq[threadIdx.x] += rq[threadIdx.x+st]; }
        __syncthreads();
    }
    if (threadIdx.x == 0) {
        float mean = rs[0] / NVTF_;
        float var = rq[0] / NVTF_ - mean * mean;
        float scale = gamma[o] * rsqrtf(var + 1e-5f);
        bnp[o*2]   = scale;
        bnp[o*2+1] = beta[o] - mean * scale;
    }
}

// ---------------- BN + ReLU, in place ----------------
__global__ __launch_bounds__(256) void k_bn(float* __restrict__ y,
        const float* __restrict__ bnp, int O, size_t total4) {
    size_t stride = (size_t)gridDim.x * blockDim.x;
    for (size_t i = (size_t)blockIdx.x * 256 + threadIdx.x; i < total4; i += stride) {
        size_t e = i * 4;
        int o = (int)((e / VT_) % O);
        float sc = bnp[o*2], sh = bnp[o*2+1];
        float4 v = *(const float4*)(y + e);
        v.x = fmaxf(fmaf(v.x, sc, sh), 0.f);
        v.y = fmaxf(fmaf(v.y, sc, sh), 0.f);
        v.z = fmaxf(fmaf(v.z, sc, sh), 0.f);
        v.w = fmaxf(fmaf(v.w, sc, sh), 0.f);
        *(float4*)(y + e) = v;
    }
}

extern "C" void kernel_launch(void* const* d_in, const int* in_sizes, int n_in,
                              void* d_out, int out_size, void* d_ws, size_t ws_size,
                              hipStream_t stream) {
    const float* x   = (const float*)d_in[0];
    const float* wg1 = (const float*)d_in[1];
    const float* wg2 = (const float*)d_in[2];
    const float* w11 = (const float*)d_in[3];
    const float* w12 = (const float*)d_in[4];
    const float* ga1 = (const float*)d_in[5];
    const float* be1 = (const float*)d_in[6];
    const float* w21 = (const float*)d_in[7];
    const float* w22 = (const float*)d_in[8];
    const float* ga2 = (const float*)d_in[9];
    const float* be2 = (const float*)d_in[10];
    const float* w31 = (const float*)d_in[11];
    const float* w32 = (const float*)d_in[12];
    const float* ga3 = (const float*)d_in[13];
    const float* be3 = (const float*)d_in[14];

    float* xout = (float*)d_out;               // (64,256,25,128) = 52,428,800
    float* gout = xout + 52428800;             // (64,128,25,25)  =  5,120,000

    float* ws = (float*)d_ws;
    // region0: a1,a2 (6,553,600) then reused as x1 (26,214,400 max)
    float* a1   = ws;
    float* a2   = ws + 3276800;
    float* x1   = ws;                          // reuse after k_g
    float* B1   = ws + 26214400;               // L1 out: 13,107,200
    float* B2   = B1 + 13107200;               // L2 out: 26,214,400
    float* psum = B2 + 26214400;               // 409,600
    float* psq  = psum + 409600;               // 409,600
    float* bnp  = psq + 409600;                // 512

    k_a<<<1600, 128, 0, stream>>>(x, wg1, wg2, a1, a2);
    k_g<<<512, 256, 0, stream>>>(a1, a2, gout);

    // layer 1: C=64 -> O=64
    k_mp<<<512, 256, 0, stream>>>(x, gout, x1, 64);
    k_gemm<<<dim3(25, 1, 64), 256, 0, stream>>>(w11, w12, x1, x, B1, psum, psq, 64, 64);
    k_stats<<<64, 256, 0, stream>>>(psum, psq, ga1, be1, bnp);
    k_bn<<<2048, 256, 0, stream>>>(B1, bnp, 64, 13107200 / 4);

    // layer 2: C=64 -> O=128
    k_mp<<<512, 256, 0, stream>>>(B1, gout, x1, 64);
    k_gemm<<<dim3(25, 2, 64), 256, 0, stream>>>(w21, w22, x1, B1, B2, psum, psq, 64, 128);
    k_stats<<<128, 256, 0, stream>>>(psum, psq, ga2, be2, bnp);
    k_bn<<<2048, 256, 0, stream>>>(B2, bnp, 128, 26214400 / 4);

    // layer 3: C=128 -> O=256
    k_mp<<<512, 256, 0, stream>>>(B2, gout, x1, 128);
    k_gemm<<<dim3(25, 4, 64), 256, 0, stream>>>(w31, w32, x1, B2, xout, psum, psq, 128, 256);
    k_stats<<<256, 256, 0, stream>>>(psum, psq, ga3, be3, bnp);
    k_bn<<<2048, 256, 0, stream>>>(xout, bnp, 256, 52428800 / 4);
}

// Round 2
// 493.011 us; speedup vs baseline: 2.2586x; 2.2586x over previous
//
#include <hip/hip_runtime.h>
#include <cstdint>

#define V_ 25
#define T_ 128
#define VT_ 3200
#define NVTF_ 204800.0f

typedef unsigned short ushort_t;
typedef __attribute__((ext_vector_type(8))) short s16x8;
typedef __attribute__((ext_vector_type(4))) float f32x4;

__device__ __forceinline__ ushort_t f2bf(float f) {
    union { float f; unsigned u; } v; v.f = f;
    unsigned r = v.u + 0x7FFFu + ((v.u >> 16) & 1u);
    return (ushort_t)(r >> 16);
}
__device__ __forceinline__ float bf2f(ushort_t h) {
    union { unsigned u; float f; } v; v.u = ((unsigned)h) << 16;
    return v.f;
}
__device__ __forceinline__ void gload16(const void* g, void* l) {
    __builtin_amdgcn_global_load_lds((const __attribute__((address_space(1))) void*)g,
                                     (__attribute__((address_space(3))) void*)l, 16, 0, 0);
}

// ---------------- a1/a2: (N,16,V,T) = wg @ x  (fp32, small) ----------------
__global__ __launch_bounds__(128) void k_a(const float* __restrict__ x,
        const float* __restrict__ wg1, const float* __restrict__ wg2,
        float* __restrict__ a1, float* __restrict__ a2) {
    int b = blockIdx.x; int n = b / V_; int v = b % V_;
    int t = threadIdx.x;
    __shared__ float w1s[1024], w2s[1024];
    for (int i = threadIdx.x; i < 1024; i += 128) { w1s[i] = wg1[i]; w2s[i] = wg2[i]; }
    __syncthreads();
    float s1[16], s2[16];
    #pragma unroll
    for (int o = 0; o < 16; o++) { s1[o] = 0.f; s2[o] = 0.f; }
    const float* xp = x + (size_t)n * 204800 + v * T_ + t;
    for (int c = 0; c < 64; c++) {
        float xv = xp[(size_t)c * VT_];
        #pragma unroll
        for (int o = 0; o < 16; o++) {
            s1[o] = fmaf(w1s[o*64+c], xv, s1[o]);
            s2[o] = fmaf(w2s[o*64+c], xv, s2[o]);
        }
    }
    float* p1 = a1 + (size_t)n * 51200 + v * T_ + t;
    float* p2 = a2 + (size_t)n * 51200 + v * T_ + t;
    #pragma unroll
    for (int o = 0; o < 16; o++) { p1[(size_t)o*VT_] = s1[o]; p2[(size_t)o*VT_] = s2[o]; }
}

// ---------------- g = softmax(a1^T a2) per (n,t): (N,T,V,V) fp32 ----------------
__global__ __launch_bounds__(256) void k_g(const float* __restrict__ a1,
        const float* __restrict__ a2, float* __restrict__ g) {
    int n = blockIdx.x >> 3; int t0 = (blockIdx.x & 7) * 16;
    __shared__ float A1s[6400], A2s[6400]; // [o][v][tt]
    for (int i = threadIdx.x; i < 6400; i += 256) {
        int o = i / 400; int r = i % 400; int v = r >> 4; int tt = r & 15;
        size_t ga = (size_t)n * 51200 + (size_t)o * VT_ + v * T_ + t0 + tt;
        A1s[i] = a1[ga];
        A2s[i] = a2[ga];
    }
    __syncthreads();
    for (int r = threadIdx.x; r < 400; r += 256) {
        int v = r >> 4; int tt = r & 15;
        float a1r[16];
        #pragma unroll
        for (int o = 0; o < 16; o++) a1r[o] = A1s[o*400 + v*16 + tt];
        float gr[25];
        float mx = -1e30f;
        for (int u = 0; u < 25; u++) {
            float s = 0.f;
            #pragma unroll
            for (int o = 0; o < 16; o++) s = fmaf(a1r[o], A2s[o*400 + u*16 + tt], s);
            gr[u] = s; mx = fmaxf(mx, s);
        }
        float sum = 0.f;
        for (int u = 0; u < 25; u++) { gr[u] = __expf(gr[u] - mx); sum += gr[u]; }
        float inv = 1.f / sum;
        float* gp = g + ((size_t)(n * T_ + t0 + tt) * V_ + v) * V_;
        for (int u = 0; u < 25; u++) gp[u] = gr[u] * inv;
    }
}

// ---------------- weight concat + bf16 convert: Wc[o][0..C)=w1, [C..2C)=w2 ----------------
__global__ void k_wcat(const float* __restrict__ w1, const float* __restrict__ w2,
        ushort_t* __restrict__ wc, int O, int C) {
    int i = blockIdx.x * 256 + threadIdx.x;
    if (i >= O * 2 * C) return;
    int o = i / (2 * C), k = i % (2 * C);
    float v = (k < C) ? w1[o * C + k] : w2[o * C + k - C];
    wc[i] = f2bf(v);
}

// ---------------- transpose x (n,c,m) fp32 -> cat1[n][m][64+c] bf16 ----------------
__global__ __launch_bounds__(256) void k_tr(const float* __restrict__ x,
        ushort_t* __restrict__ cat1) {
    int n = blockIdx.y, m0 = blockIdx.x * 64;
    __shared__ ushort_t L[64 * 67]; // [c][m] pad 67
    for (int i = threadIdx.x; i < 1024; i += 256) {
        int c = i >> 4, mc = i & 15;
        float4 v = *(const float4*)(x + ((size_t)n * 64 + c) * VT_ + m0 + mc * 4);
        int base = c * 67 + mc * 4;
        L[base]   = f2bf(v.x); L[base+1] = f2bf(v.y);
        L[base+2] = f2bf(v.z); L[base+3] = f2bf(v.w);
    }
    __syncthreads();
    for (int i = threadIdx.x; i < 512; i += 256) {
        int m = i >> 3, cc = i & 7;
        s16x8 pk;
        #pragma unroll
        for (int j = 0; j < 8; j++) pk[j] = (short)L[(cc * 8 + j) * 67 + m];
        *(s16x8*)(cat1 + ((size_t)n * VT_ + m0 + m) * 128 + 64 + cc * 8) = pk;
    }
}

// ---------------- message passing in [m][k] bf16 layout ----------------
// cat[n][m][0..C) = sum_u g[n,t,v,u] * cat[n][u*T+t][C..2C)
__global__ __launch_bounds__(256) void k_mp(const float* __restrict__ g,
        ushort_t* __restrict__ cat, int C) {
    int K2 = 2 * C;
    int n = blockIdx.y, t0 = blockIdx.x * 8;
    __shared__ float Gs[5200]; // [tt][v][u] pad 26
    const float* gsrc = g + ((size_t)n * T_ + t0) * 625;
    for (int i = threadIdx.x; i < 5000; i += 256) {
        int tt = i / 625, r = i % 625, v = r / 25, u = r % 25;
        Gs[(tt * 25 + v) * 26 + u] = gsrc[i];
    }
    __syncthreads();
    int NC8 = C >> 3;
    int total = 8 * 25 * NC8;
    for (int it = threadIdx.x; it < total; it += 256) {
        int tt = it / (25 * NC8);
        int r = it % (25 * NC8);
        int v = r / NC8, ch = r % NC8;
        const ushort_t* xb = cat + ((size_t)n * VT_ + t0 + tt) * K2 + C + ch * 8;
        float acc[8] = {0.f,0.f,0.f,0.f,0.f,0.f,0.f,0.f};
        const float* gw = &Gs[(tt * 25 + v) * 26];
        for (int u = 0; u < 25; u++) {
            float wv = gw[u];
            s16x8 xv = *(const s16x8*)(xb + (size_t)u * T_ * K2);
            #pragma unroll
            for (int j = 0; j < 8; j++) acc[j] = fmaf(wv, bf2f((ushort_t)xv[j]), acc[j]);
        }
        s16x8 pk;
        #pragma unroll
        for (int j = 0; j < 8; j++) pk[j] = (short)f2bf(acc[j]);
        *(s16x8*)(cat + ((size_t)n * VT_ + v * T_ + t0 + tt) * K2 + ch * 8) = pk;
    }
}

// ---------------- MFMA GEMM: y[o][m] = sum_k Wc[o][k] * Bcat[m][k] ----------------
// TOUT=0: store bf16 [n][m][O] to yt; TOUT=1: store fp32 [n][O][m] to fout
template<int TOUT>
__global__ __launch_bounds__(256) void k_gemm(const ushort_t* __restrict__ Wc,
        const ushort_t* __restrict__ Bcat, ushort_t* __restrict__ yt,
        float* __restrict__ fout,
        float* __restrict__ psum, float* __restrict__ psq, int K2, int O) {
    __shared__ __align__(16) char smem[24576]; // A: 8KB @0, B: 16KB @8192
    int n = blockIdx.z, m0 = blockIdx.x * 128, o0 = blockIdx.y * 64;
    int tid = threadIdx.x, w = tid >> 6, lane = tid & 63;
    int wo = w >> 1, wm = w & 1, l15 = lane & 15, g4 = lane >> 4;
    f32x4 acc[2][4] = {};
    for (int k0 = 0; k0 < K2; k0 += 64) {
        #pragma unroll
        for (int i = 0; i < 2; i++) {  // A: 64 rows x 8 chunks (swizzled)
            int s = i * 256 + w * 64 + lane;
            int r = s >> 3, csw = s & 7, c = csw ^ (r & 7);
            gload16(Wc + (size_t)(o0 + r) * K2 + k0 + c * 8,
                    smem + (i * 256 + w * 64) * 16);
        }
        #pragma unroll
        for (int i = 0; i < 4; i++) {  // B: 128 rows x 8 chunks (swizzled)
            int s = i * 256 + w * 64 + lane;
            int r = s >> 3, csw = s & 7, c = csw ^ (r & 7);
            gload16(Bcat + ((size_t)n * VT_ + m0 + r) * K2 + k0 + c * 8,
                    smem + 8192 + (i * 256 + w * 64) * 16);
        }
        __syncthreads();
        #pragma unroll
        for (int kk = 0; kk < 2; kk++) {
            s16x8 aF[2], bF[4];
            #pragma unroll
            for (int oi = 0; oi < 2; oi++) {
                int row = wo * 32 + oi * 16 + l15;
                int ch = kk * 4 + g4;
                aF[oi] = *(const s16x8*)(smem + row * 128 + 16 * (ch ^ (row & 7)));
            }
            #pragma unroll
            for (int mi = 0; mi < 4; mi++) {
                int row = wm * 64 + mi * 16 + l15;
                int ch = kk * 4 + g4;
                bF[mi] = *(const s16x8*)(smem + 8192 + row * 128 + 16 * (ch ^ (row & 7)));
            }
            #pragma unroll
            for (int oi = 0; oi < 2; oi++)
                #pragma unroll
                for (int mi = 0; mi < 4; mi++)
                    acc[oi][mi] = __builtin_amdgcn_mfma_f32_16x16x32_bf16(
                        aF[oi], bF[mi], acc[oi][mi], 0, 0, 0);
        }
        __syncthreads();
    }
    // BN partial stats from fp32 accumulators
    #pragma unroll
    for (int oi = 0; oi < 2; oi++) {
        #pragma unroll
        for (int b = 0; b < 4; b++) {
            float s = 0.f, q = 0.f;
            #pragma unroll
            for (int mi = 0; mi < 4; mi++) {
                float v0 = acc[oi][mi][b];
                s += v0; q = fmaf(v0, v0, q);
            }
            #pragma unroll
            for (int msk = 1; msk < 16; msk <<= 1) {
                s += __shfl_xor(s, msk, 16);
                q += __shfl_xor(q, msk, 16);
            }
            if (l15 == 0) {
                int o = o0 + wo * 32 + oi * 16 + 4 * g4 + b;
                int p = (n * 25 + blockIdx.x) * 2 + wm;
                psum[(size_t)o * 3200 + p] = s;
                psq [(size_t)o * 3200 + p] = q;
            }
        }
    }
    if (TOUT == 0) {
        // per-wave LDS restage -> bf16 [m][O]
        ushort_t* Lw = (ushort_t*)smem + w * 2176; // [64 m][34]
        #pragma unroll
        for (int oi = 0; oi < 2; oi++)
            #pragma unroll
            for (int mi = 0; mi < 4; mi++)
                #pragma unroll
                for (int b = 0; b < 4; b++)
                    Lw[(mi * 16 + l15) * 34 + oi * 16 + 4 * g4 + b] = f2bf(acc[oi][mi][b]);
        #pragma unroll
        for (int i = 0; i < 4; i++) {
            int item = i * 64 + lane;
            int ml = item >> 2, oc = item & 3;
            s16x8 pk;
            #pragma unroll
            for (int j = 0; j < 8; j++) pk[j] = (short)Lw[ml * 34 + oc * 8 + j];
            *(s16x8*)(yt + ((size_t)n * VT_ + m0 + wm * 64 + ml) * O
                         + o0 + wo * 32 + oc * 8) = pk;
        }
    } else {
        // per-wave LDS restage -> fp32 [O][m] (d_out layout), two o-halves
        float* Lf = (float*)(smem + w * 4352); // [16 o][68 m]
        #pragma unroll
        for (int oi = 0; oi < 2; oi++) {
            #pragma unroll
            for (int mi = 0; mi < 4; mi++)
                #pragma unroll
                for (int b = 0; b < 4; b++)
                    Lf[(4 * g4 + b) * 68 + mi * 16 + l15] = acc[oi][mi][b];
            #pragma unroll
            for (int i = 0; i < 4; i++) {
                int item = i * 64 + lane;
                int ol = item >> 4, mc = item & 15;
                f32x4 v = *(const f32x4*)(Lf + ol * 68 + mc * 4);
                *(f32x4*)(fout + ((size_t)n * O + o0 + wo * 32 + oi * 16 + ol) * VT_
                               + m0 + wm * 64 + mc * 4) = v;
            }
        }
    }
}

// ---------------- finalize per-channel stats -> scale/shift ----------------
__global__ __launch_bounds__(256) void k_stats(const float* __restrict__ psum,
        const float* __restrict__ psq, const float* __restrict__ gamma,
        const float* __restrict__ beta, float* __restrict__ bnp) {
    int o = blockIdx.x;
    float s = 0.f, q = 0.f;
    for (int i = threadIdx.x; i < 3200; i += 256) {
        s += psum[(size_t)o*3200+i]; q += psq[(size_t)o*3200+i];
    }
    __shared__ float rs[256], rq[256];
    rs[threadIdx.x] = s; rq[threadIdx.x] = q;
    __syncthreads();
    for (int st = 128; st > 0; st >>= 1) {
        if (threadIdx.x < st) { rs[threadIdx.x] += rs[threadIdx.x+st]; rq[threadIdx.x] += rq[threadIdx.x+st]; }
        __syncthreads();
    }
    if (threadIdx.x == 0) {
        float mean = rs[0] / NVTF_;
        float var = rq[0] / NVTF_ - mean * mean;
        float scale = gamma[o] * rsqrtf(var + 1e-5f);
        bnp[o*2]   = scale;
        bnp[o*2+1] = beta[o] - mean * scale;
    }
}

// ---------------- BN+ReLU elementwise bf16 [m][O] -> catn[m][C2..2C2) ----------------
__global__ __launch_bounds__(256) void k_bnc(const ushort_t* __restrict__ y,
        const float* __restrict__ bnp, ushort_t* __restrict__ catn, int O, size_t total8) {
    size_t stride = (size_t)gridDim.x * 256;
    int O8 = O >> 3;
    for (size_t i = (size_t)blockIdx.x * 256 + threadIdx.x; i < total8; i += stride) {
        size_t mr = i / O8; int oc = (int)(i % O8);
        s16x8 v = ((const s16x8*)y)[i];
        s16x8 pk;
        #pragma unroll
        for (int j = 0; j < 8; j++) {
            int o = oc * 8 + j;
            float f = fmaf(bf2f((ushort_t)v[j]), bnp[2*o], bnp[2*o+1]);
            pk[j] = (short)f2bf(fmaxf(f, 0.f));
        }
        *(s16x8*)(catn + mr * (size_t)(2 * O) + O + oc * 8) = pk;
    }
}

// ---------------- BN + ReLU, fp32 in place (layer 3) ----------------
__global__ __launch_bounds__(256) void k_bn(float* __restrict__ y,
        const float* __restrict__ bnp, int O, size_t total4) {
    size_t stride = (size_t)gridDim.x * 256;
    for (size_t i = (size_t)blockIdx.x * 256 + threadIdx.x; i < total4; i += stride) {
        size_t e = i * 4;
        int o = (int)((e / VT_) % O);
        float sc = bnp[o*2], sh = bnp[o*2+1];
        float4 v = *(const float4*)(y + e);
        v.x = fmaxf(fmaf(v.x, sc, sh), 0.f);
        v.y = fmaxf(fmaf(v.y, sc, sh), 0.f);
        v.z = fmaxf(fmaf(v.z, sc, sh), 0.f);
        v.w = fmaxf(fmaf(v.w, sc, sh), 0.f);
        *(float4*)(y + e) = v;
    }
}

extern "C" void kernel_launch(void* const* d_in, const int* in_sizes, int n_in,
                              void* d_out, int out_size, void* d_ws, size_t ws_size,
                              hipStream_t stream) {
    const float* x   = (const float*)d_in[0];
    const float* wg1 = (const float*)d_in[1];
    const float* wg2 = (const float*)d_in[2];
    const float* w11 = (const float*)d_in[3];
    const float* w12 = (const float*)d_in[4];
    const float* ga1 = (const float*)d_in[5];
    const float* be1 = (const float*)d_in[6];
    const float* w21 = (const float*)d_in[7];
    const float* w22 = (const float*)d_in[8];
    const float* ga2 = (const float*)d_in[9];
    const float* be2 = (const float*)d_in[10];
    const float* w31 = (const float*)d_in[11];
    const float* w32 = (const float*)d_in[12];
    const float* ga3 = (const float*)d_in[13];
    const float* be3 = (const float*)d_in[14];

    float* xout = (float*)d_out;               // (64,256,25,128) fp32
    float* gout = xout + 52428800;             // (64,128,25,25) fp32

    float* ws = (float*)d_ws;
    // region A (13,107,200 fl = 52.4MB): a1+a2 -> y1 (bf16) -> y2 (bf16)
    float* a1 = ws;
    float* a2 = ws + 3276800;
    ushort_t* y1 = (ushort_t*)ws;              // 13.1M halfs
    ushort_t* y2 = (ushort_t*)ws;              // 26.2M halfs
    // region B (26,214,400 fl = 104.9MB): cat1 (bf16 26.2M halfs) -> cat3 (52.4M halfs)
    ushort_t* cat1 = (ushort_t*)(ws + 13107200);
    ushort_t* cat3 = (ushort_t*)(ws + 13107200);
    // region C (13,107,200 fl): cat2 (26.2M halfs)
    ushort_t* cat2 = (ushort_t*)(ws + 39321600);
    float* psum = ws + 52428800;               // 819,200
    float* psq  = ws + 53248000;               // 819,200
    ushort_t* Wc = (ushort_t*)(ws + 54067200); // 172,032 halfs
    float* bnp  = ws + 54153216;               // 512
    ushort_t* Wc1 = Wc, *Wc2 = Wc + 8192, *Wc3 = Wc + 40960;

    k_a<<<1600, 128, 0, stream>>>(x, wg1, wg2, a1, a2);
    k_g<<<512, 256, 0, stream>>>(a1, a2, gout);
    k_wcat<<<32, 256, 0, stream>>>(w11, w12, Wc1, 64, 64);
    k_wcat<<<128, 256, 0, stream>>>(w21, w22, Wc2, 128, 64);
    k_wcat<<<512, 256, 0, stream>>>(w31, w32, Wc3, 256, 128);
    k_tr<<<dim3(50, 64), 256, 0, stream>>>(x, cat1);

    // layer 1: C=64 -> O=64
    k_mp<<<dim3(16, 64), 256, 0, stream>>>(gout, cat1, 64);
    k_gemm<0><<<dim3(25, 1, 64), 256, 0, stream>>>(Wc1, cat1, y1, nullptr, psum, psq, 128, 64);
    k_stats<<<64, 256, 0, stream>>>(psum, psq, ga1, be1, bnp);
    k_bnc<<<2048, 256, 0, stream>>>(y1, bnp, cat2, 64, (size_t)64*3200*64/8);

    // layer 2: C=64 -> O=128
    k_mp<<<dim3(16, 64), 256, 0, stream>>>(gout, cat2, 64);
    k_gemm<0><<<dim3(25, 2, 64), 256, 0, stream>>>(Wc2, cat2, y2, nullptr, psum, psq, 128, 128);
    k_stats<<<128, 256, 0, stream>>>(psum, psq, ga2, be2, bnp);
    k_bnc<<<2048, 256, 0, stream>>>(y2, bnp, cat3, 128, (size_t)64*3200*128/8);

    // layer 3: C=128 -> O=256, fp32 out to d_out
    k_mp<<<dim3(16, 64), 256, 0, stream>>>(gout, cat3, 128);
    k_gemm<1><<<dim3(25, 4, 64), 256, 0, stream>>>(Wc3, cat3, nullptr, xout, psum, psq, 256, 256);
    k_stats<<<256, 256, 0, stream>>>(psum, psq, ga3, be3, bnp);
    k_bn<<<2048, 256, 0, stream>>>(xout, bnp, 256, 52428800 / 4);
}

// Round 4
// 393.259 us; speedup vs baseline: 2.8315x; 1.2537x over previous
//
#include <hip/hip_runtime.h>
#include <cstdint>

#define V_ 25
#define T_ 128
#define VT_ 3200
#define NVTF_ 204800.0f

typedef unsigned short ushort_t;
typedef __attribute__((ext_vector_type(8))) short s16x8;
typedef __attribute__((ext_vector_type(4))) float f32x4;

__device__ __forceinline__ ushort_t f2bf(float f) {
    union { float f; unsigned u; } v; v.f = f;
    unsigned r = v.u + 0x7FFFu + ((v.u >> 16) & 1u);
    return (ushort_t)(r >> 16);
}
__device__ __forceinline__ float bf2f(ushort_t h) {
    union { unsigned u; float f; } v; v.u = ((unsigned)h) << 16;
    return v.f;
}
__device__ __forceinline__ void gload16(const void* g, void* l) {
    __builtin_amdgcn_global_load_lds((const __attribute__((address_space(1))) void*)g,
                                     (__attribute__((address_space(3))) void*)l, 16, 0, 0);
}

// ---------------- k_a: a1/a2 = wg @ x (bf16 out) + cat1 2nd-half transpose ----------------
__global__ __launch_bounds__(128) void k_a(const float* __restrict__ x,
        const float* __restrict__ wg1, const float* __restrict__ wg2,
        ushort_t* __restrict__ a1, ushort_t* __restrict__ a2,
        ushort_t* __restrict__ cat1) {
    int b = blockIdx.x; int n = b / V_; int v = b % V_;
    int t = threadIdx.x;
    __shared__ float w1s[1024], w2s[1024];
    for (int i = threadIdx.x; i < 1024; i += 128) { w1s[i] = wg1[i]; w2s[i] = wg2[i]; }
    __syncthreads();
    float s1[16], s2[16];
    #pragma unroll
    for (int o = 0; o < 16; o++) { s1[o] = 0.f; s2[o] = 0.f; }
    s16x8 xs[8];
    const float* xp = x + (size_t)n * 204800 + v * T_ + t;
    #pragma unroll
    for (int c = 0; c < 64; c++) {
        float xv = xp[(size_t)c * VT_];
        xs[c >> 3][c & 7] = (short)f2bf(xv);
        #pragma unroll
        for (int o = 0; o < 16; o++) {
            s1[o] = fmaf(w1s[o*64+c], xv, s1[o]);
            s2[o] = fmaf(w2s[o*64+c], xv, s2[o]);
        }
    }
    size_t abase = (size_t)n * 51200 + v * T_ + t;
    #pragma unroll
    for (int o = 0; o < 16; o++) {
        a1[abase + (size_t)o * VT_] = f2bf(s1[o]);
        a2[abase + (size_t)o * VT_] = f2bf(s2[o]);
    }
    ushort_t* cp = cat1 + ((size_t)(n * VT_ + v * T_ + t)) * 128 + 64;
    #pragma unroll
    for (int ch = 0; ch < 8; ch++) *(s16x8*)(cp + ch * 8) = xs[ch];
}

// ---------------- k_g: g = softmax(a1^T a2), fp32 (d_out) + bf16 copy ----------------
__global__ __launch_bounds__(256) void k_g(const ushort_t* __restrict__ a1,
        const ushort_t* __restrict__ a2, float* __restrict__ g,
        ushort_t* __restrict__ gb) {
    int n = blockIdx.x >> 3; int t0 = (blockIdx.x & 7) * 16;
    __shared__ float A1s[6400], A2s[6400]; // [o][v][tt]
    for (int i = threadIdx.x; i < 6400; i += 256) {
        int o = i / 400; int r = i % 400; int v = r >> 4; int tt = r & 15;
        size_t ga = (size_t)n * 51200 + (size_t)o * VT_ + v * T_ + t0 + tt;
        A1s[i] = bf2f(a1[ga]);
        A2s[i] = bf2f(a2[ga]);
    }
    __syncthreads();
    for (int r = threadIdx.x; r < 400; r += 256) {
        int v = r >> 4; int tt = r & 15;
        float a1r[16];
        #pragma unroll
        for (int o = 0; o < 16; o++) a1r[o] = A1s[o*400 + v*16 + tt];
        float gr[25];
        float mx = -1e30f;
        for (int u = 0; u < 25; u++) {
            float s = 0.f;
            #pragma unroll
            for (int o = 0; o < 16; o++) s = fmaf(a1r[o], A2s[o*400 + u*16 + tt], s);
            gr[u] = s; mx = fmaxf(mx, s);
        }
        float sum = 0.f;
        for (int u = 0; u < 25; u++) { gr[u] = __expf(gr[u] - mx); sum += gr[u]; }
        float inv = 1.f / sum;
        size_t goff = ((size_t)(n * T_ + t0 + tt) * V_ + v) * V_;
        float* gp = g + goff;
        ushort_t* gbp = gb + goff;
        for (int u = 0; u < 25; u++) {
            float val = gr[u] * inv;
            gp[u] = val;
            gbp[u] = f2bf(val);
        }
    }
}

// ---------------- weight concat + bf16 ----------------
__global__ void k_wcat(const float* __restrict__ w1, const float* __restrict__ w2,
        ushort_t* __restrict__ wc, int O, int C) {
    int i = blockIdx.x * 256 + threadIdx.x;
    if (i >= O * 2 * C) return;
    int o = i / (2 * C), k = i % (2 * C);
    float v = (k < C) ? w1[o * C + k] : w2[o * C + k - C];
    wc[i] = f2bf(v);
}

// ---------------- k_bnmp: [BN+ReLU] + message passing ----------------
// Stage rows (u,tt) of C channels (optionally BN'd) into LDS; optionally write
// them as cat 2nd half; compute MP over u -> cat 1st half.
template<int C, bool BN, bool PASS>
__global__ __launch_bounds__(256) void k_bnmp(const ushort_t* __restrict__ yin,
        const ushort_t* __restrict__ gb, const float* __restrict__ bnp,
        ushort_t* __restrict__ cat, int in_stride, int in_off) {
    const int NC8 = C / 8;
    const int ITEMS = 25 * 8 * NC8;
    int n = blockIdx.y, t0 = blockIdx.x * 8;
    __shared__ float Gs[5200];        // [tt][v][u] pad 26
    __shared__ ushort_t Ys[25 * 8 * C]; // [u][tt][c]
    const ushort_t* gsrc = gb + ((size_t)(n * T_ + t0)) * 625;
    for (int i = threadIdx.x; i < 5000; i += 256) {
        int tt = i / 625, r = i % 625, v = r / 25, u = r % 25;
        Gs[(tt * 25 + v) * 26 + u] = bf2f(gsrc[i]);
    }
    // stage (and pass-through) input rows
    for (int i = threadIdx.x; i < ITEMS; i += 256) {
        int u = i / (8 * NC8);
        int rem = i % (8 * NC8);
        int tt = rem / NC8, ch = rem % NC8;
        size_t srow = (size_t)n * VT_ + u * T_ + t0 + tt;
        s16x8 vv = *(const s16x8*)(yin + srow * in_stride + in_off + ch * 8);
        s16x8 pk;
        if (BN) {
            #pragma unroll
            for (int j = 0; j < 8; j++) {
                int o = ch * 8 + j;
                float f = fmaf(bf2f((ushort_t)vv[j]), bnp[2*o], bnp[2*o+1]);
                pk[j] = (short)f2bf(fmaxf(f, 0.f));
            }
        } else pk = vv;
        *(s16x8*)(&Ys[(u * 8 + tt) * C + ch * 8]) = pk;
        if (PASS) *(s16x8*)(cat + srow * (2 * C) + C + ch * 8) = pk;
    }
    __syncthreads();
    // message passing
    for (int i = threadIdx.x; i < ITEMS; i += 256) {
        int v = i / (8 * NC8);
        int rem = i % (8 * NC8);
        int tt = rem / NC8, ch = rem % NC8;
        const float* gw = &Gs[(tt * 25 + v) * 26];
        float acc[8] = {0.f,0.f,0.f,0.f,0.f,0.f,0.f,0.f};
        #pragma unroll
        for (int u = 0; u < 25; u++) {
            float wv = gw[u];
            s16x8 xv = *(const s16x8*)(&Ys[(u * 8 + tt) * C + ch * 8]);
            #pragma unroll
            for (int j = 0; j < 8; j++) acc[j] = fmaf(wv, bf2f((ushort_t)xv[j]), acc[j]);
        }
        s16x8 pk;
        #pragma unroll
        for (int j = 0; j < 8; j++) pk[j] = (short)f2bf(acc[j]);
        *(s16x8*)(cat + ((size_t)n * VT_ + v * T_ + t0 + tt) * (2 * C) + ch * 8) = pk;
    }
}

// ---------------- MFMA GEMM: y[o][m] = sum_k Wc[o][k] * Bcat[m][k] ----------------
// TOUT=0: bf16 [n][m][O] to yt; TOUT=2: bf16 [n][O][m] to yt
template<int TOUT>
__global__ __launch_bounds__(256) void k_gemm(const ushort_t* __restrict__ Wc,
        const ushort_t* __restrict__ Bcat, ushort_t* __restrict__ yt,
        float* __restrict__ psum, float* __restrict__ psq, int K2, int O) {
    __shared__ __align__(16) char smem[24576]; // A: 8KB @0, B: 16KB @8192
    int n = blockIdx.z, m0 = blockIdx.x * 128, o0 = blockIdx.y * 64;
    int tid = threadIdx.x, w = tid >> 6, lane = tid & 63;
    int wo = w >> 1, wm = w & 1, l15 = lane & 15, g4 = lane >> 4;
    f32x4 acc[2][4] = {};
    for (int k0 = 0; k0 < K2; k0 += 64) {
        #pragma unroll
        for (int i = 0; i < 2; i++) {  // A: 64 rows x 8 chunks (swizzled)
            int s = i * 256 + w * 64 + lane;
            int r = s >> 3, csw = s & 7, c = csw ^ (r & 7);
            gload16(Wc + (size_t)(o0 + r) * K2 + k0 + c * 8,
                    smem + (i * 256 + w * 64) * 16);
        }
        #pragma unroll
        for (int i = 0; i < 4; i++) {  // B: 128 rows x 8 chunks (swizzled)
            int s = i * 256 + w * 64 + lane;
            int r = s >> 3, csw = s & 7, c = csw ^ (r & 7);
            gload16(Bcat + ((size_t)n * VT_ + m0 + r) * K2 + k0 + c * 8,
                    smem + 8192 + (i * 256 + w * 64) * 16);
        }
        __syncthreads();
        #pragma unroll
        for (int kk = 0; kk < 2; kk++) {
            s16x8 aF[2], bF[4];
            #pragma unroll
            for (int oi = 0; oi < 2; oi++) {
                int row = wo * 32 + oi * 16 + l15;
                int ch = kk * 4 + g4;
                aF[oi] = *(const s16x8*)(smem + row * 128 + 16 * (ch ^ (row & 7)));
            }
            #pragma unroll
            for (int mi = 0; mi < 4; mi++) {
                int row = wm * 64 + mi * 16 + l15;
                int ch = kk * 4 + g4;
                bF[mi] = *(const s16x8*)(smem + 8192 + row * 128 + 16 * (ch ^ (row & 7)));
            }
            #pragma unroll
            for (int oi = 0; oi < 2; oi++)
                #pragma unroll
                for (int mi = 0; mi < 4; mi++)
                    acc[oi][mi] = __builtin_amdgcn_mfma_f32_16x16x32_bf16(
                        aF[oi], bF[mi], acc[oi][mi], 0, 0, 0);
        }
        __syncthreads();
    }
    // BN partial stats from fp32 accumulators
    #pragma unroll
    for (int oi = 0; oi < 2; oi++) {
        #pragma unroll
        for (int b = 0; b < 4; b++) {
            float s = 0.f, q = 0.f;
            #pragma unroll
            for (int mi = 0; mi < 4; mi++) {
                float v0 = acc[oi][mi][b];
                s += v0; q = fmaf(v0, v0, q);
            }
            #pragma unroll
            for (int msk = 1; msk < 16; msk <<= 1) {
                s += __shfl_xor(s, msk, 16);
                q += __shfl_xor(q, msk, 16);
            }
            if (l15 == 0) {
                int o = o0 + wo * 32 + oi * 16 + 4 * g4 + b;
                int p = (n * 25 + blockIdx.x) * 2 + wm;
                psum[(size_t)o * 3200 + p] = s;
                psq [(size_t)o * 3200 + p] = q;
            }
        }
    }
    if (TOUT == 0) {
        // per-wave LDS restage -> bf16 [m][O]
        ushort_t* Lw = (ushort_t*)smem + w * 2176; // [64 m][34]
        #pragma unroll
        for (int oi = 0; oi < 2; oi++)
            #pragma unroll
            for (int mi = 0; mi < 4; mi++)
                #pragma unroll
                for (int b = 0; b < 4; b++)
                    Lw[(mi * 16 + l15) * 34 + oi * 16 + 4 * g4 + b] = f2bf(acc[oi][mi][b]);
        #pragma unroll
        for (int i = 0; i < 4; i++) {
            int item = i * 64 + lane;
            int ml = item >> 2, oc = item & 3;
            s16x8 pk;
            #pragma unroll
            for (int j = 0; j < 8; j++) pk[j] = (short)Lw[ml * 34 + oc * 8 + j];
            *(s16x8*)(yt + ((size_t)n * VT_ + m0 + wm * 64 + ml) * O
                         + o0 + wo * 32 + oc * 8) = pk;
        }
    } else {
        // per-wave LDS restage -> bf16 [O][m]
        ushort_t* Lw = (ushort_t*)smem + w * 1152; // [16 o][72 m]
        #pragma unroll
        for (int oi = 0; oi < 2; oi++) {
            #pragma unroll
            for (int mi = 0; mi < 4; mi++)
                #pragma unroll
                for (int b = 0; b < 4; b++)
                    Lw[(4 * g4 + b) * 72 + mi * 16 + l15] = f2bf(acc[oi][mi][b]);
            #pragma unroll
            for (int it = 0; it < 2; it++) {
                int item = it * 64 + lane;
                int ol = item >> 3, mc = item & 7;
                s16x8 pk;
                #pragma unroll
                for (int j = 0; j < 8; j++) pk[j] = (short)Lw[ol * 72 + mc * 8 + j];
                *(s16x8*)(yt + ((size_t)n * O + o0 + wo * 32 + oi * 16 + ol) * VT_
                             + m0 + wm * 64 + mc * 8) = pk;
            }
        }
    }
}

// ---------------- finalize per-channel stats -> scale/shift ----------------
__global__ __launch_bounds__(256) void k_stats(const float* __restrict__ psum,
        const float* __restrict__ psq, const float* __restrict__ gamma,
        const float* __restrict__ beta, float* __restrict__ bnp) {
    int o = blockIdx.x;
    float s = 0.f, q = 0.f;
    for (int i = threadIdx.x; i < 3200; i += 256) {
        s += psum[(size_t)o*3200+i]; q += psq[(size_t)o*3200+i];
    }
    __shared__ float rs[256], rq[256];
    rs[threadIdx.x] = s; rq[threadIdx.x] = q;
    __syncthreads();
    for (int st = 128; st > 0; st >>= 1) {
        if (threadIdx.x < st) { rs[threadIdx.x] += rs[threadIdx.x+st]; rq[threadIdx.x] += rq[threadIdx.x+st]; }
        __syncthreads();
    }
    if (threadIdx.x == 0) {
        float mean = rs[0] / NVTF_;
        float var = rq[0] / NVTF_ - mean * mean;
        float scale = gamma[o] * rsqrtf(var + 1e-5f);
        bnp[o*2]   = scale;
        bnp[o*2+1] = beta[o] - mean * scale;
    }
}

// ---------------- final BN + ReLU: bf16 y3 [O][m] -> fp32 d_out ----------------
__global__ __launch_bounds__(256) void k_bnf(const ushort_t* __restrict__ y3,
        const float* __restrict__ bnp, float* __restrict__ xout) {
    const size_t total = 6553600; // 52.4M elems / 8
    size_t stride = (size_t)gridDim.x * 256;
    for (size_t i = (size_t)blockIdx.x * 256 + threadIdx.x; i < total; i += stride) {
        int o = (int)((i / 400) & 255);
        float sc = bnp[2*o], sh = bnp[2*o+1];
        s16x8 v = ((const s16x8*)y3)[i];
        float* op = xout + i * 8;
        float4 f0, f1;
        f0.x = fmaxf(fmaf(bf2f((ushort_t)v[0]), sc, sh), 0.f);
        f0.y = fmaxf(fmaf(bf2f((ushort_t)v[1]), sc, sh), 0.f);
        f0.z = fmaxf(fmaf(bf2f((ushort_t)v[2]), sc, sh), 0.f);
        f0.w = fmaxf(fmaf(bf2f((ushort_t)v[3]), sc, sh), 0.f);
        f1.x = fmaxf(fmaf(bf2f((ushort_t)v[4]), sc, sh), 0.f);
        f1.y = fmaxf(fmaf(bf2f((ushort_t)v[5]), sc, sh), 0.f);
        f1.z = fmaxf(fmaf(bf2f((ushort_t)v[6]), sc, sh), 0.f);
        f1.w = fmaxf(fmaf(bf2f((ushort_t)v[7]), sc, sh), 0.f);
        *(float4*)op = f0;
        *(float4*)(op + 4) = f1;
    }
}

extern "C" void kernel_launch(void* const* d_in, const int* in_sizes, int n_in,
                              void* d_out, int out_size, void* d_ws, size_t ws_size,
                              hipStream_t stream) {
    const float* x   = (const float*)d_in[0];
    const float* wg1 = (const float*)d_in[1];
    const float* wg2 = (const float*)d_in[2];
    const float* w11 = (const float*)d_in[3];
    const float* w12 = (const float*)d_in[4];
    const float* ga1 = (const float*)d_in[5];
    const float* be1 = (const float*)d_in[6];
    const float* w21 = (const float*)d_in[7];
    const float* w22 = (const float*)d_in[8];
    const float* ga2 = (const float*)d_in[9];
    const float* be2 = (const float*)d_in[10];
    const float* w31 = (const float*)d_in[11];
    const float* w32 = (const float*)d_in[12];
    const float* ga3 = (const float*)d_in[13];
    const float* be3 = (const float*)d_in[14];

    float* xout = (float*)d_out;               // (64,256,25,128) fp32
    float* gout = xout + 52428800;             // (64,128,25,25) fp32

    float* ws = (float*)d_ws;
    // region A [0, 6.55M fl): a1,a2 bf16 (6.55M us) -> y1 bf16 (13.1M us)
    ushort_t* a1 = (ushort_t*)ws;
    ushort_t* a2 = a1 + 3276800;
    ushort_t* y1 = (ushort_t*)ws;
    // region BC [6.55M, 32.75M fl): cat1 (26.2M us) -> y2 (26.2M us) -> y3 (52.4M us)
    ushort_t* cat1 = (ushort_t*)(ws + 6553600);
    ushort_t* y2   = cat1;
    ushort_t* y3   = cat1;
    // region C2 [32.75M, 45.85M fl): cat2 (26.2M us)
    ushort_t* cat2 = (ushort_t*)(ws + 32768000);
    // region D [45.85M, 72.05M fl): cat3 (52.4M us)
    ushort_t* cat3 = (ushort_t*)(ws + 45875200);
    ushort_t* gb   = (ushort_t*)(ws + 72089600); // 5.12M us
    float* psum = ws + 74649600;               // 819,200 fl
    float* psq  = ws + 75468800;               // 819,200 fl
    ushort_t* Wc = (ushort_t*)(ws + 76288000); // 172,032 us = 86,016 fl
    float* bnp  = ws + 76374016;               // 512 fl  (FIX: was +43008, overlapped Wc3)
    ushort_t* Wc1 = Wc, *Wc2 = Wc + 8192, *Wc3 = Wc + 40960;

    k_a<<<1600, 128, 0, stream>>>(x, wg1, wg2, a1, a2, cat1);
    k_g<<<512, 256, 0, stream>>>(a1, a2, gout, gb);
    k_wcat<<<32, 256, 0, stream>>>(w11, w12, Wc1, 64, 64);
    k_wcat<<<128, 256, 0, stream>>>(w21, w22, Wc2, 128, 64);
    k_wcat<<<512, 256, 0, stream>>>(w31, w32, Wc3, 256, 128);

    // layer 1: C=64 -> O=64
    k_bnmp<64, false, false><<<dim3(16, 64), 256, 0, stream>>>(cat1, gb, nullptr, cat1, 128, 64);
    k_gemm<0><<<dim3(25, 1, 64), 256, 0, stream>>>(Wc1, cat1, y1, psum, psq, 128, 64);
    k_stats<<<64, 256, 0, stream>>>(psum, psq, ga1, be1, bnp);

    // layer 2: C=64 -> O=128  (BN(y1)+MP fused)
    k_bnmp<64, true, true><<<dim3(16, 64), 256, 0, stream>>>(y1, gb, bnp, cat2, 64, 0);
    k_gemm<0><<<dim3(25, 2, 64), 256, 0, stream>>>(Wc2, cat2, y2, psum, psq, 128, 128);
    k_stats<<<128, 256, 0, stream>>>(psum, psq, ga2, be2, bnp);

    // layer 3: C=128 -> O=256  (BN(y2)+MP fused)
    k_bnmp<128, true, true><<<dim3(16, 64), 256, 0, stream>>>(y2, gb, bnp, cat3, 128, 0);
    k_gemm<2><<<dim3(25, 4, 64), 256, 0, stream>>>(Wc3, cat3, y3, psum, psq, 256, 256);
    k_stats<<<256, 256, 0, stream>>>(psum, psq, ga3, be3, bnp);
    k_bnf<<<2048, 256, 0, stream>>>(y3, bnp, xout);
}